// Round 7
// baseline (145.586 us; speedup 1.0000x reference)
//
#include <hip/hip_runtime.h>
#include <math.h>

// AttnSum3d via bf16-split MFMA + symmetry + bound-shifted softmax:
//   X = x*mask, scaled by sqrt(log2 e); Y = [bf16_hi|bf16_lo] (L x 256 bf16).
//   S' = Y Y^T = S*log2(e) (symmetric). Cauchy-Schwarz bound C_m = n_m*Nmax
//   (norms of scaled rows) >= column max, overshoot <= Nmax^2/4 ~ 68 (log2
//   units) -- safe for f32 exp2 with no max tracking at all.
//   csum[m] = sum_l exp2(S'[l,m]-C_m);  Q_m = -C_m - log2(csum_m);
//   r[l] = sum_m exp2(S'[l,m]+Q_m);  out[b,0,d] = (1/L) sum_l X[l,d] r[l];
//   attn_mean = 1/L exactly.
// Upper-triangle tiles only (wrapped distance d: row ib owns jb=(ib+d)&15,
// d=0..7, +8 if ib<8); each tile yields row-direction AND col-direction
// partials. 1024 quarter-strip blocks (2-3 tiles), BK=64, 32KB LDS,
// 4 blocks/CU. Y pre-swizzled: 16B slot s at position (s&~7)|((s^row)&7).
// R7 FIX: stage LINEARLY from Y so LDS inherits the global swizzle (R6
// staged with a second XOR, un-swizzling LDS while reads still XOR'd ->
// 7/8 of S tiles were k-misaligned garbage; rule: swizzle applied once).

constexpr int NB = 16, NL = 2048, ND = 128;
constexpr int ROWS_US = 256;  // ushorts per Y row (K_eff = 256 bf16)
constexpr int NSLOT = 12;     // 0..3 own quarters (row-dir), 4..11 col-dir d=1..8

typedef __attribute__((ext_vector_type(8))) short short8;
typedef __attribute__((ext_vector_type(4))) float f32x4;

#define EXP2(x) __builtin_amdgcn_exp2f(x)

__device__ __forceinline__ unsigned short f2bf(float f) {
  unsigned u = __builtin_bit_cast(unsigned, f);
  u += 0x7FFFu + ((u >> 16) & 1u);
  return (unsigned short)(u >> 16);
}
__device__ __forceinline__ float bf2f(unsigned short h) {
  unsigned u = ((unsigned)h) << 16;
  return __builtin_bit_cast(float, u);
}

__device__ __forceinline__ void stage16(const unsigned short* g, unsigned short* l) {
  __builtin_amdgcn_global_load_lds(
      (const __attribute__((address_space(1))) unsigned int*)g,
      (__attribute__((address_space(3))) unsigned int*)l, 16, 0, 0);
}

// prep: scale by sqrt(log2 e)*mask, bf16-split, swizzled store, row norms^2.
__global__ __launch_bounds__(256) void k_prep(const float* __restrict__ x,
                                              const float* __restrict__ mask,
                                              unsigned short* __restrict__ Y,
                                              float* __restrict__ nsq) {
  const int gid = blockIdx.x * 256 + threadIdx.x;  // one float4 (4 d-elems)
  const int row = gid >> 5;
  const int dq = gid & 31;
  const float4 v = reinterpret_cast<const float4*>(x)[gid];
  const float m = mask[row] * 1.2011224087864498f;  // sqrt(log2 e)
  const float f0 = v.x * m, f1 = v.y * m, f2 = v.z * m, f3 = v.w * m;
  const unsigned short h0 = f2bf(f0), h1 = f2bf(f1), h2 = f2bf(f2), h3 = f2bf(f3);
  const unsigned short e0 = f2bf(f0 - bf2f(h0)), e1 = f2bf(f1 - bf2f(h1)),
                       e2 = f2bf(f2 - bf2f(h2)), e3 = f2bf(f3 - bf2f(h3));
  unsigned short* Yr = Y + (size_t)row * ROWS_US;
  const int sx = dq >> 1, half8 = (dq & 1) * 4;
  const int pos = (sx & 8) | ((sx ^ row) & 7);  // XOR within 8-slot groups
  *reinterpret_cast<ushort4*>(Yr + pos * 8 + half8) = make_ushort4(h0, h1, h2, h3);
  *reinterpret_cast<ushort4*>(Yr + (16 + pos) * 8 + half8) = make_ushort4(e0, e1, e2, e3);
  float ss = f0 * f0 + f1 * f1 + f2 * f2 + f3 * f3;
#pragma unroll
  for (int mk = 1; mk < 32; mk <<= 1) ss += __shfl_xor(ss, mk);
  if (dq == 0) nsq[row] = ss;
}

__global__ __launch_bounds__(256) void k_nmax(const float* __restrict__ nsq,
                                              float* __restrict__ nmax) {
  const int b = blockIdx.x;
  const int tid = threadIdx.x;
  float m = 0.f;
  for (int i = tid; i < NL; i += 256) m = fmaxf(m, nsq[b * NL + i]);
#pragma unroll
  for (int mk = 1; mk < 64; mk <<= 1) m = fmaxf(m, __shfl_xor(m, mk));
  __shared__ float red[4];
  if ((tid & 63) == 0) red[tid >> 6] = m;
  __syncthreads();
  if (tid == 0) nmax[b] = fmaxf(fmaxf(red[0], red[1]), fmaxf(red[2], red[3]));
}

__global__ __launch_bounds__(256) void k_carr(const float* __restrict__ nsq,
                                              const float* __restrict__ nmax,
                                              float* __restrict__ C) {
  const int i = blockIdx.x * 256 + threadIdx.x;
  C[i] = sqrtf(nsq[i] * nmax[i >> 11]);
}

// Block decode: xcd = sid&7 owns 2 batches; 64 quarter-strips per batch.
#define STRIP_DECODE()                                     \
  const int sid = blockIdx.x;                              \
  const int idx = sid >> 3;                                \
  const int b = ((sid & 7) << 1) | (idx >> 6);             \
  const int rest = idx & 63;                               \
  const int ib = rest >> 2, q = rest & 3;                  \
  const int d0 = 2 * q;                                    \
  const int nt = (q == 3 && ib < 8) ? 3 : 2;               \
  const int row0 = ib * 128;                               \
  const int tid = threadIdx.x;                             \
  const int lane = tid & 63, wave = tid >> 6;              \
  const int wr = wave >> 1, wc = wave & 1;                 \
  const int lhi = lane >> 4, llo = lane & 15;

// 128x128 tile GEMM, BK=64 x4 chunks. Declares acc[4][4] (f32x4).
// Staging is LINEAR (LDS inherits Y's per-row XOR swizzle); reads XOR by row.
#define TILE_GEMM(Yb, row0, col0)                                                     \
  f32x4 acc[4][4];                                                                    \
  _Pragma("unroll") for (int rs = 0; rs < 4; ++rs)                                    \
      _Pragma("unroll") for (int cs = 0; cs < 4; ++cs)                                \
          acc[rs][cs] = f32x4{0.f, 0.f, 0.f, 0.f};                                    \
  for (int c = 0; c < 4; ++c) {                                                       \
    __syncthreads();                                                                  \
    _Pragma("unroll") for (int it = 0; it < 4; ++it) {                                \
      const int idx2 = tid + 256 * it;                                                \
      const int r = idx2 >> 3, s = idx2 & 7;                                          \
      stage16(Yb + (size_t)(row0 + r) * ROWS_US + (8 * c + s) * 8, At + idx2 * 8);    \
      stage16(Yb + (size_t)(col0 + r) * ROWS_US + (8 * c + s) * 8, Bt + idx2 * 8);    \
    }                                                                                 \
    __syncthreads();                                                                  \
    _Pragma("unroll") for (int t4 = 0; t4 < 2; ++t4) {                                \
      const int sl = 4 * t4 + lhi;                                                    \
      short8 af[4], bf[4];                                                            \
      _Pragma("unroll") for (int qq = 0; qq < 4; ++qq) {                              \
        const int ra = 64 * wr + 16 * qq + llo;                                       \
        af[qq] = *(const short8*)(At + ra * 64 + ((sl ^ (ra & 7)) << 3));             \
        const int rb = 64 * wc + 16 * qq + llo;                                       \
        bf[qq] = *(const short8*)(Bt + rb * 64 + ((sl ^ (rb & 7)) << 3));             \
      }                                                                               \
      _Pragma("unroll") for (int rs = 0; rs < 4; ++rs)                                \
          _Pragma("unroll") for (int cs = 0; cs < 4; ++cs)                            \
              acc[rs][cs] = __builtin_amdgcn_mfma_f32_16x16x32_bf16(af[rs], bf[cs],   \
                                                                    acc[rs][cs], 0, 0, 0); \
    }                                                                                 \
  }

// ---- pass 1: csum partials (pure sums, no max tracking) ----
__global__ __launch_bounds__(256, 4) void k_esum(const unsigned short* __restrict__ Y,
                                                 const float* __restrict__ C,
                                                 float* __restrict__ pcs) {
  __shared__ alignas(128) char lds[32768];
  unsigned short* At = (unsigned short*)lds;
  unsigned short* Bt = (unsigned short*)(lds + 16384);
  float* ebuf = (float*)lds;           // [2 wr][128]
  float* rbuf = (float*)(lds + 2048);  // [2 wc][128]
  STRIP_DECODE()
  const unsigned short* Yb = Y + (size_t)b * NL * ROWS_US;

  float Cr[16];
#pragma unroll
  for (int rs = 0; rs < 4; ++rs)
#pragma unroll
    for (int rg = 0; rg < 4; ++rg)
      Cr[rs * 4 + rg] = C[b * NL + row0 + 64 * wr + 16 * rs + 4 * lhi + rg];

  float racc[16];
#pragma unroll
  for (int i = 0; i < 16; ++i) racc[i] = 0.f;

  for (int dt = 0; dt < nt; ++dt) {
    const int d = d0 + dt;
    const int col0 = ((ib + d) & 15) * 128;
    float Cc[4];
#pragma unroll
    for (int cs = 0; cs < 4; ++cs) Cc[cs] = C[b * NL + col0 + 64 * wc + 16 * cs + llo];
    TILE_GEMM(Yb, row0, col0)
    // row-direction: contributes to csum[row0+i] (sum over this tile's cols)
#pragma unroll
    for (int rs = 0; rs < 4; ++rs)
#pragma unroll
      for (int rg = 0; rg < 4; ++rg) {
        float t = 0.f;
#pragma unroll
        for (int cs = 0; cs < 4; ++cs) t += EXP2(acc[rs][cs][rg] - Cr[rs * 4 + rg]);
        racc[rs * 4 + rg] += t;
      }
    // col-direction: contributes to csum[col0+j] (sum over this tile's rows)
    if (d != 0) {
      __syncthreads();
#pragma unroll
      for (int cs = 0; cs < 4; ++cs) {
        float u = 0.f;
#pragma unroll
        for (int rs = 0; rs < 4; ++rs)
#pragma unroll
          for (int rg = 0; rg < 4; ++rg) u += EXP2(acc[rs][cs][rg] - Cc[cs]);
        u += __shfl_xor(u, 16);
        u += __shfl_xor(u, 32);
        if (lhi == 0) ebuf[wr * 128 + 64 * wc + 16 * cs + llo] = u;
      }
      __syncthreads();
      if (tid < 128)
        pcs[((size_t)(b * NSLOT + 3 + d)) * NL + col0 + tid] = ebuf[tid] + ebuf[128 + tid];
    }
  }
#pragma unroll
  for (int i = 0; i < 16; ++i) {
    float s = racc[i];
#pragma unroll
    for (int mk = 1; mk < 16; mk <<= 1) s += __shfl_xor(s, mk);
    racc[i] = s;
  }
  __syncthreads();
  if (llo == 0) {
#pragma unroll
    for (int rs = 0; rs < 4; ++rs)
#pragma unroll
      for (int rg = 0; rg < 4; ++rg)
        rbuf[wc * 128 + 64 * wr + 16 * rs + 4 * lhi + rg] = racc[rs * 4 + rg];
  }
  __syncthreads();
  if (tid < 128)
    pcs[((size_t)(b * NSLOT + q)) * NL + row0 + tid] = rbuf[tid] + rbuf[128 + tid];
}

// csum partials -> Q = -C - log2(csum)
__global__ __launch_bounds__(256) void k_comb(const float* __restrict__ pcs,
                                              const float* __restrict__ C,
                                              float* __restrict__ Q) {
  const int i = blockIdx.x * 256 + threadIdx.x;  // b*NL + row
  const int b = i >> 11, row = i & (NL - 1);
  const int o = row >> 7;
  float s = 0.f;
#pragma unroll
  for (int c = 0; c < NSLOT; ++c) {
    if (c == 11 && o < 8) continue;  // slot 11 (d=8) only for owners >= 8
    s += pcs[((size_t)(b * NSLOT + c)) * NL + row];
  }
  Q[i] = -C[i] - __log2f(s);
}

// ---- pass 2: r partials: r[l] = sum_m exp2(S' + Q_m) ----
__global__ __launch_bounds__(256, 4) void k_r(const unsigned short* __restrict__ Y,
                                              const float* __restrict__ Qa,
                                              float* __restrict__ rp) {
  __shared__ alignas(128) char lds[32768];
  unsigned short* At = (unsigned short*)lds;
  unsigned short* Bt = (unsigned short*)(lds + 16384);
  float* ebuf = (float*)lds;
  float* rbuf = (float*)(lds + 2048);
  STRIP_DECODE()
  const unsigned short* Yb = Y + (size_t)b * NL * ROWS_US;

  float Qr[16];
#pragma unroll
  for (int rs = 0; rs < 4; ++rs)
#pragma unroll
    for (int rg = 0; rg < 4; ++rg)
      Qr[rs * 4 + rg] = Qa[b * NL + row0 + 64 * wr + 16 * rs + 4 * lhi + rg];

  float racc[16];
#pragma unroll
  for (int i = 0; i < 16; ++i) racc[i] = 0.f;

  for (int dt = 0; dt < nt; ++dt) {
    const int d = d0 + dt;
    const int col0 = ((ib + d) & 15) * 128;
    float Qc[4];
#pragma unroll
    for (int cs = 0; cs < 4; ++cs) Qc[cs] = Qa[b * NL + col0 + 64 * wc + 16 * cs + llo];
    TILE_GEMM(Yb, row0, col0)
    // row-direction: r[row0+i] += sum over cols m of exp2(S' + Q_m)
#pragma unroll
    for (int rs = 0; rs < 4; ++rs)
#pragma unroll
      for (int rg = 0; rg < 4; ++rg) {
        float t = 0.f;
#pragma unroll
        for (int cs = 0; cs < 4; ++cs) t += EXP2(acc[rs][cs][rg] + Qc[cs]);
        racc[rs * 4 + rg] += t;
      }
    // col-direction: r[col0+j] += sum over rows m of exp2(S' + Q_m)
    if (d != 0) {
      __syncthreads();
#pragma unroll
      for (int cs = 0; cs < 4; ++cs) {
        float u = 0.f;
#pragma unroll
        for (int rs = 0; rs < 4; ++rs)
#pragma unroll
          for (int rg = 0; rg < 4; ++rg) u += EXP2(acc[rs][cs][rg] + Qr[rs * 4 + rg]);
        u += __shfl_xor(u, 16);
        u += __shfl_xor(u, 32);
        if (lhi == 0) ebuf[wr * 128 + 64 * wc + 16 * cs + llo] = u;
      }
      __syncthreads();
      if (tid < 128)
        rp[((size_t)(b * NSLOT + 3 + d)) * NL + col0 + tid] = ebuf[tid] + ebuf[128 + tid];
    }
  }
#pragma unroll
  for (int i = 0; i < 16; ++i) {
    float s = racc[i];
#pragma unroll
    for (int mk = 1; mk < 16; mk <<= 1) s += __shfl_xor(s, mk);
    racc[i] = s;
  }
  __syncthreads();
  if (llo == 0) {
#pragma unroll
    for (int rs = 0; rs < 4; ++rs)
#pragma unroll
      for (int rg = 0; rg < 4; ++rg)
        rbuf[wc * 128 + 64 * wr + 16 * rs + 4 * lhi + rg] = racc[rs * 4 + rg];
  }
  __syncthreads();
  if (tid < 128)
    rp[((size_t)(b * NSLOT + q)) * NL + row0 + tid] = rbuf[tid] + rbuf[128 + tid];
}

// ---- pass 3a: per-(b,seg) partial of sum_l w[l]*x[l,:] ----
__global__ __launch_bounds__(256) void k_outp(const float* __restrict__ x,
                                              const float* __restrict__ mask,
                                              const float* __restrict__ rp,
                                              float* __restrict__ partial) {
  const int b = blockIdx.y;
  const int seg = blockIdx.x;  // 16 segments of 128 rows; owner block == seg
  const int tid = threadIdx.x;
  const int l0 = seg * 128;
  __shared__ float w_s[128];
  __shared__ float4 red[8][32];
  if (tid < 128) {
    float s = 0.f;
#pragma unroll
    for (int c = 0; c < NSLOT; ++c) {
      if (c == 11 && seg < 8) continue;
      s += rp[((size_t)(b * NSLOT + c)) * NL + l0 + tid];
    }
    w_s[tid] = s * mask[b * NL + l0 + tid];
  }
  __syncthreads();
  const int dq = tid & 31;
  const int rg = tid >> 5;
  float4 acc = make_float4(0.f, 0.f, 0.f, 0.f);
#pragma unroll 4
  for (int i = 0; i < 16; ++i) {
    const int l = 8 * i + rg;
    const float w = w_s[l];
    const float4 v = *reinterpret_cast<const float4*>(x + ((size_t)b * NL + l0 + l) * ND + 4 * dq);
    acc.x += w * v.x; acc.y += w * v.y; acc.z += w * v.z; acc.w += w * v.w;
  }
  red[rg][dq] = acc;
  __syncthreads();
  if (rg == 0) {
    float4 s = acc;
#pragma unroll
    for (int k = 1; k < 8; ++k) {
      const float4 t = red[k][dq];
      s.x += t.x; s.y += t.y; s.z += t.z; s.w += t.w;
    }
    *reinterpret_cast<float4*>(partial + ((size_t)(b * 16 + seg)) * ND + 4 * dq) = s;
  }
}

// ---- pass 3b: finalize out + constant attn_mean fill ----
__global__ __launch_bounds__(1024) void k_fin(const float* __restrict__ partial,
                                              float* __restrict__ out) {
  const int gid = blockIdx.x * 1024 + threadIdx.x;  // 0..32767
  if (gid < NB * ND) {
    const int b = gid >> 7, d = gid & (ND - 1);
    float s = 0.f;
#pragma unroll
    for (int k = 0; k < 16; ++k) s += partial[(size_t)(b * 16 + k) * ND + d];
    out[gid] = s * (1.0f / NL);
  }
  out[NB * ND + gid] = 1.0f / NL;  // attn_mean == 1/L exactly
}

extern "C" void kernel_launch(void* const* d_in, const int* in_sizes, int n_in,
                              void* d_out, int out_size, void* d_ws, size_t ws_size,
                              hipStream_t stream) {
  const float* x = (const float*)d_in[0];     // [16,2048,128] f32
  const float* mask = (const float*)d_in[1];  // [16,2048] f32
  float* out = (float*)d_out;

  unsigned short* Y = (unsigned short*)d_ws;                   // 16.8 MB
  float* nsq = (float*)(Y + (size_t)NB * NL * ROWS_US);        // [NB*NL]
  float* nmax = nsq + NB * NL;                                 // [NB]
  float* C = nmax + 16;                                        // [NB*NL]
  float* pcs = C + NB * NL;                                    // [NB*NSLOT*NL]
  float* rp = pcs;                                             // alias (pcs consumed first)
  float* Q = pcs + (size_t)NB * NSLOT * NL;                    // [NB*NL]
  float* partial = Q + NB * NL;                                // [NB*16*ND]

  k_prep<<<dim3(NB * NL * ND / 4 / 256), 256, 0, stream>>>(x, mask, Y, nsq);
  k_nmax<<<NB, 256, 0, stream>>>(nsq, nmax);
  k_carr<<<dim3(NB * NL / 256), 256, 0, stream>>>(nsq, nmax, C);
  k_esum<<<dim3(1024), 256, 0, stream>>>(Y, C, pcs);
  k_comb<<<dim3(NB * NL / 256), 256, 0, stream>>>(pcs, C, Q);
  k_r<<<dim3(1024), 256, 0, stream>>>(Y, Q, rp);
  k_outp<<<dim3(16, NB), 256, 0, stream>>>(x, mask, rp, partial);
  k_fin<<<32, 1024, 0, stream>>>(partial, out);
}